// Round 4
// baseline (354.431 us; speedup 1.0000x reference)
//
#include <hip/hip_runtime.h>
#include <cstddef>

#define H 1024
#define V 15000
#define NE 4
#define B 32
#define S 2048
#define EPS 1e-6f
#define CH 16
#define T0 128  // S / CH
#define NU 938  // ceil(V/16)

__device__ __forceinline__ float wave_sum(float x) {
#pragma unroll
  for (int off = 32; off > 0; off >>= 1) x += __shfl_down(x, off);
  return x;
}

// K1: per-vocab-row inverse RMS of embedding. one wave per row.
__global__ __launch_bounds__(256) void k_vocab(const float* __restrict__ emb,
                                               float* __restrict__ invr1) {
  const int gw = (blockIdx.x * blockDim.x + threadIdx.x) >> 6;  // row
  const int lane = threadIdx.x & 63;
  if (gw >= V) return;
  const float4* row = (const float4*)(emb + (size_t)gw * H);
  float s = 0.f;
#pragma unroll
  for (int j = 0; j < 4; ++j) {
    const float4 f = row[lane + 64 * j];
    s += f.x * f.x + f.y * f.y + f.z * f.z + f.w * f.w;
  }
  s = wave_sum(s);
  if (lane == 0) invr1[gw] = rsqrtf(s * (1.f / H) + EPS);
}

// Phase A: per-chunk local layer-1 scans (zero initial state).
__global__ __launch_bounds__(1024, 8) void k_scanA(
    const int* __restrict__ windows, const float* __restrict__ emb,
    const float* __restrict__ norm1_w, const float* __restrict__ decay_logit,
    const float* __restrict__ invr1, float* __restrict__ local1) {
  __shared__ int tok_l[T0];
  __shared__ float iv_l[T0];
  const int b = blockIdx.x / CH, c = blockIdx.x % CH;
  const int h = threadIdx.x;
  if (h < T0) {
    const int tok = windows[b * S + c * T0 + h];
    tok_l[h] = tok << 10;
    iv_l[h] = invr1[tok];
  }
  const float d1 = 1.f / (1.f + expf(-decay_logit[h]));
  const float gw = norm1_w[h] * (1.f - d1);
  __syncthreads();
  float s = 0.f;
  for (int t0 = 0; t0 < T0; t0 += 8) {
    float e[8], cv[8];
#pragma unroll
    for (int k = 0; k < 8; ++k) {
      e[k] = emb[(size_t)tok_l[t0 + k] + h];
      cv[k] = iv_l[t0 + k] * gw;
    }
#pragma unroll
    for (int k = 0; k < 8; ++k) s = s * d1 + e[k] * cv[k];
  }
  local1[(size_t)(b * CH + c) * H + h] = s;
}

// Phase B: combine chunk locals -> chunk-start states, es1, pooled invRMS.
__global__ __launch_bounds__(1024) void k_scanB(
    const int* __restrict__ windows, const float* __restrict__ emb,
    const float* __restrict__ decay_logit, const float* __restrict__ local1,
    float* __restrict__ s1start, float* __restrict__ es1,
    float* __restrict__ invp) {
  __shared__ float red[16];
  const int b = blockIdx.x, h = threadIdx.x;
  const float d1 = 1.f / (1.f + expf(-decay_logit[h]));
  float dT = d1;
#pragma unroll
  for (int i = 0; i < 7; ++i) dT *= dT;  // d1^128
  float Sv = 0.f;
  for (int c = 0; c < CH; ++c) {
    const size_t idx = (size_t)(b * CH + c) * H + h;
    s1start[idx] = Sv;
    Sv = dT * Sv + local1[idx];
  }
  const int tl = windows[b * S + S - 1];
  const float v = emb[(size_t)tl * H + h] + Sv;
  es1[b * H + h] = v;
  const float q = wave_sum(v * v);
  if ((h & 63) == 0) red[h >> 6] = q;
  __syncthreads();
  if (h == 0) {
    float t = 0.f;
#pragma unroll
    for (int i = 0; i < 16; ++i) t += red[i];
    invp[b] = rsqrtf(t * (1.f / H) + EPS);
  }
}

// K4: selected-expert matvec: out[b,d] = relu(sum_h p[b,h] * W[e_b,d,h])
__global__ __launch_bounds__(256) void k_expert(const float* __restrict__ src,
    const float* __restrict__ invp, const float* __restrict__ n2w,
    const float* __restrict__ Wl, const int* __restrict__ experts,
    float* __restrict__ outp) {
  __shared__ float p[H];
  const int b = blockIdx.x >> 4;
  const int dblk = blockIdx.x & 15;
  const int tid = threadIdx.x;
  const float ip = invp[b];
  for (int j = tid; j < H; j += 256) p[j] = src[b * H + j] * ip * n2w[j];
  __syncthreads();
  const float* W = Wl + (size_t)experts[b] * H * H;
  const int wave = tid >> 6, lane = tid & 63;
#pragma unroll 1
  for (int i = 0; i < 16; ++i) {
    const int dd = dblk * 64 + wave * 16 + i;
    const float* wr = W + (size_t)dd * H;
    float s = 0.f;
#pragma unroll
    for (int j = 0; j < 16; ++j) s += wr[lane + 64 * j] * p[lane + 64 * j];
    s = wave_sum(s);
    if (lane == 0) outp[b * H + dd] = fmaxf(s, 0.f);
  }
}

// Phase C: recompute s1 from chunk-start states; per-(b,t) sumsq of x1.
__global__ __launch_bounds__(1024, 8) void k_sumsqC(
    const int* __restrict__ windows, const float* __restrict__ emb,
    const float* __restrict__ norm1_w, const float* __restrict__ decay_logit,
    const float* __restrict__ invr1, const float* __restrict__ s1start,
    const float* __restrict__ out1, float* __restrict__ r2) {
  __shared__ int tok_l[T0];
  __shared__ float iv_l[T0];
  __shared__ float q[16 * H];  // 64 KB
  const int b = blockIdx.x / CH, c = blockIdx.x % CH;
  const int h = threadIdx.x;
  if (h < T0) {
    const int tok = windows[b * S + c * T0 + h];
    tok_l[h] = tok << 10;
    iv_l[h] = invr1[tok];
  }
  const float d1 = 1.f / (1.f + expf(-decay_logit[h]));
  const float gw = norm1_w[h] * (1.f - d1);
  const float o1 = out1[b * H + h];
  float s1 = s1start[(size_t)(b * CH + c) * H + h];
  __syncthreads();
  const int wv = h >> 6, lane = h & 63;
  for (int sb = 0; sb < T0 / 16; ++sb) {
#pragma unroll
    for (int g = 0; g < 2; ++g) {
      float e[8], cv[8];
#pragma unroll
      for (int k = 0; k < 8; ++k) {
        const int t = sb * 16 + g * 8 + k;
        e[k] = emb[(size_t)tok_l[t] + h];
        cv[k] = iv_l[t] * gw;
      }
#pragma unroll
      for (int k = 0; k < 8; ++k) {
        s1 = s1 * d1 + e[k] * cv[k];
        const float x1 = e[k] + s1 + o1;
        q[(g * 8 + k) * H + h] = x1 * x1;
      }
    }
    __syncthreads();
    const float4* q4 = (const float4*)(q + wv * H);
    float ssum = 0.f;
#pragma unroll
    for (int j = 0; j < 4; ++j) {
      const float4 f = q4[lane + 64 * j];
      ssum += f.x + f.y + f.z + f.w;
    }
    ssum = wave_sum(ssum);
    if (lane == 0) r2[b * S + c * T0 + sb * 16 + wv] = ssum;
    __syncthreads();
  }
}

// r2 sum -> inverse rms, in place.
__global__ __launch_bounds__(256) void k_r2fin(float* __restrict__ r2) {
  const int i = blockIdx.x * 256 + threadIdx.x;
  r2[i] = rsqrtf(r2[i] * (1.f / H) + EPS);
}

// Phase D: per-chunk local layer-2 scans (s1 recomputed from chunk starts).
__global__ __launch_bounds__(1024, 8) void k_scanD(
    const int* __restrict__ windows, const float* __restrict__ emb,
    const float* __restrict__ norm1_w, const float* __restrict__ decay_logit,
    const float* __restrict__ invr1, const float* __restrict__ s1start,
    const float* __restrict__ out1, const float* __restrict__ r2inv,
    float* __restrict__ local2, float* __restrict__ x1last) {
  __shared__ int tok_l[T0];
  __shared__ float iv_l[T0];
  __shared__ float rv_l[T0];
  const int b = blockIdx.x / CH, c = blockIdx.x % CH;
  const int h = threadIdx.x;
  if (h < T0) {
    const int tok = windows[b * S + c * T0 + h];
    tok_l[h] = tok << 10;
    iv_l[h] = invr1[tok];
    rv_l[h] = r2inv[b * S + c * T0 + h];
  }
  const float d1 = 1.f / (1.f + expf(-decay_logit[h]));
  const float g1 = norm1_w[h] * (1.f - d1);
  const float d2 = 1.f / (1.f + expf(-decay_logit[H + h]));
  const float g2 = norm1_w[H + h] * (1.f - d2);
  const float o1 = out1[b * H + h];
  float s1 = s1start[(size_t)(b * CH + c) * H + h];
  __syncthreads();
  float s2 = 0.f, x1 = 0.f;
  for (int t0 = 0; t0 < T0; t0 += 8) {
    float e[8], cv[8], rc[8];
#pragma unroll
    for (int k = 0; k < 8; ++k) {
      e[k] = emb[(size_t)tok_l[t0 + k] + h];
      cv[k] = iv_l[t0 + k] * g1;
      rc[k] = rv_l[t0 + k] * g2;
    }
#pragma unroll
    for (int k = 0; k < 8; ++k) {
      s1 = s1 * d1 + e[k] * cv[k];
      x1 = e[k] + s1 + o1;
      s2 = s2 * d2 + x1 * rc[k];
    }
  }
  local2[(size_t)(b * CH + c) * H + h] = s2;
  if (c == CH - 1) x1last[b * H + h] = x1;
}

// Phase E: combine layer-2 chunk locals -> es2 + pooled invRMS.
__global__ __launch_bounds__(1024) void k_scanE(
    const float* __restrict__ decay_logit, const float* __restrict__ local2,
    const float* __restrict__ x1last, float* __restrict__ es2,
    float* __restrict__ invp) {
  __shared__ float red[16];
  const int b = blockIdx.x, h = threadIdx.x;
  const float d2 = 1.f / (1.f + expf(-decay_logit[H + h]));
  float dT = d2;
#pragma unroll
  for (int i = 0; i < 7; ++i) dT *= dT;  // d2^128
  float Sv = 0.f;
  for (int c = 0; c < CH; ++c)
    Sv = dT * Sv + local2[(size_t)(b * CH + c) * H + h];
  const float v = x1last[b * H + h] + Sv;
  es2[b * H + h] = v;
  const float q = wave_sum(v * v);
  if ((h & 63) == 0) red[h >> 6] = q;
  __syncthreads();
  if (h == 0) {
    float t = 0.f;
#pragma unroll
    for (int i = 0; i < 16; ++i) t += red[i];
    invp[32 + b] = rsqrtf(t * (1.f / H) + EPS);
  }
}

// K7: final residual + final RMSNorm -> fstate
__global__ __launch_bounds__(256) void k_fstate(const float* __restrict__ es2,
    const float* __restrict__ out2, const float* __restrict__ fnw,
    float* __restrict__ fst) {
  __shared__ float red[4];
  const int b = blockIdx.x, tid = threadIdx.x;
  float4 x = ((const float4*)(es2 + b * H))[tid];
  const float4 y = ((const float4*)(out2 + b * H))[tid];
  x.x += y.x; x.y += y.y; x.z += y.z; x.w += y.w;
  float s = x.x * x.x + x.y * x.y + x.z * x.z + x.w * x.w;
  s = wave_sum(s);
  if ((tid & 63) == 0) red[tid >> 6] = s;
  __syncthreads();
  const float ir =
      rsqrtf((red[0] + red[1] + red[2] + red[3]) * (1.f / H) + EPS);
  const float4 w = ((const float4*)fnw)[tid];
  float4 o;
  o.x = x.x * ir * w.x; o.y = x.y * ir * w.y;
  o.z = x.z * ir * w.z; o.w = x.w * ir * w.w;
  ((float4*)(fst + b * H))[tid] = o;
}

// K8 v3: split-K register-blocked skinny GEMM.
// Block = (vblk, bgrp, hhalf); LDS = 16 b-rows x 512 h = 32 KB (4-5 blk/CU).
// Wave = 4 subgroups x 16 lanes; subgroup owns 4 vocab rows; K-depth 512.
// lv double-buffered to keep next global loads in flight during FMAs.
__global__ __launch_bounds__(256) void k_logits(const float* __restrict__ fst,
    const float* __restrict__ lm, float* __restrict__ part) {
  __shared__ float4 fs4[16 * 128];  // 32 KB
  const int hh = blockIdx.x & 1;
  const int bgrp = (blockIdx.x >> 1) & 1;
  const int vblk = blockIdx.x >> 2;  // 0..234
  const int tid = threadIdx.x;
  for (int j = tid; j < 16 * 128; j += 256) {
    const int bb = j >> 7, q = j & 127;
    fs4[j] = ((const float4*)fst)[(bgrp * 16 + bb) * 256 + hh * 128 + q];
  }
  __syncthreads();
  const int wave = tid >> 6, lane = tid & 63;
  const int sg = lane >> 4;   // 0..3
  const int c = lane & 15;    // 0..15
  const int u = vblk * 4 + wave;
  if (u >= NU) return;
  const int v0 = u * 16 + sg * 4;
  const float4* rp[4];
#pragma unroll
  for (int i = 0; i < 4; ++i) {
    int r = v0 + i;
    if (r > V - 1) r = V - 1;
    rp[i] = (const float4*)(lm + (size_t)r * H) + hh * 128;
  }
  float acc[4][16];
#pragma unroll
  for (int i = 0; i < 4; ++i)
#pragma unroll
    for (int bb = 0; bb < 16; ++bb) acc[i][bb] = 0.f;
  float4 lv[4], lvn[4];
#pragma unroll
  for (int i = 0; i < 4; ++i) lv[i] = rp[i][c];
#pragma unroll 1
  for (int jj = 0; jj < 8; ++jj) {
    const int hoff = c + 16 * jj;
    if (jj < 7) {
#pragma unroll
      for (int i = 0; i < 4; ++i) lvn[i] = rp[i][hoff + 16];
    }
#pragma unroll
    for (int bb = 0; bb < 16; ++bb) {
      const float4 fv = fs4[bb * 128 + hoff];
#pragma unroll
      for (int i = 0; i < 4; ++i) {
        acc[i][bb] += lv[i].x * fv.x + lv[i].y * fv.y + lv[i].z * fv.z +
                      lv[i].w * fv.w;
      }
    }
#pragma unroll
    for (int i = 0; i < 4; ++i) lv[i] = lvn[i];
  }
#pragma unroll
  for (int off = 1; off < 16; off <<= 1)
#pragma unroll
    for (int i = 0; i < 4; ++i)
#pragma unroll
      for (int bb = 0; bb < 16; ++bb)
        acc[i][bb] += __shfl_xor(acc[i][bb], off);
  if (c == 0) {
    float* pdst = part + (size_t)hh * B * V + (size_t)bgrp * 16 * V;
#pragma unroll
    for (int bb = 0; bb < 16; ++bb)
#pragma unroll
      for (int i = 0; i < 4; ++i) {
        const int r = v0 + i;
        if (r < V) pdst[(size_t)bb * V + r] = acc[i][bb];
      }
  }
}

// K9: combine split-K partials.
__global__ __launch_bounds__(256) void k_comb(const float* __restrict__ part,
                                              float* __restrict__ outp) {
  const int i = blockIdx.x * 256 + threadIdx.x;
  if (i < B * V) outp[i] = part[i] + part[B * V + i];
}

extern "C" void kernel_launch(void* const* d_in, const int* in_sizes, int n_in,
                              void* d_out, int out_size, void* d_ws,
                              size_t ws_size, hipStream_t stream) {
  const int* windows = (const int*)d_in[0];
  const int* experts = (const int*)d_in[2];
  const float* emb = (const float*)d_in[3];
  const float* norm1_w = (const float*)d_in[4];
  const float* decay_logit = (const float*)d_in[5];
  const float* norm2_w = (const float*)d_in[6];
  const float* Wexp = (const float*)d_in[7];
  const float* final_norm_w = (const float*)d_in[8];
  const float* lm_head = (const float*)d_in[9];
  float* outp = (float*)d_out;

  float* ws = (float*)d_ws;
  float* invr1 = ws;                       // 15360
  float* local1 = invr1 + 15360;           // B*CH*H
  float* s1start = local1 + B * CH * H;    // B*CH*H
  float* local2 = s1start + B * CH * H;    // B*CH*H
  float* out1 = local2 + B * CH * H;       // B*H
  float* out2 = out1 + B * H;              // B*H
  float* es1 = out2 + B * H;               // B*H
  float* es2 = es1 + B * H;                // B*H
  float* x1last = es2 + B * H;             // B*H
  float* fst = x1last + B * H;             // B*H
  float* invp = fst + B * H;               // 64
  float* r2 = invp + 64;                   // B*S
  // part aliases local1..local2 (1.57M floats, dead by k_logits time);
  // needs 2*B*V = 960000 floats.
  float* part = local1;

  k_vocab<<<(V * 64 + 255) / 256, 256, 0, stream>>>(emb, invr1);
  k_scanA<<<B * CH, 1024, 0, stream>>>(windows, emb, norm1_w, decay_logit,
                                       invr1, local1);
  k_scanB<<<B, 1024, 0, stream>>>(windows, emb, decay_logit, local1, s1start,
                                  es1, invp);
  k_expert<<<B * 16, 256, 0, stream>>>(es1, invp, norm2_w, Wexp, experts,
                                       out1);
  k_sumsqC<<<B * CH, 1024, 0, stream>>>(windows, emb, norm1_w, decay_logit,
                                        invr1, s1start, out1, r2);
  k_r2fin<<<(B * S) / 256, 256, 0, stream>>>(r2);
  k_scanD<<<B * CH, 1024, 0, stream>>>(windows, emb, norm1_w, decay_logit,
                                       invr1, s1start, out1, r2, local2,
                                       x1last);
  k_scanE<<<B, 1024, 0, stream>>>(decay_logit, local2, x1last, es2, invp);
  k_expert<<<B * 16, 256, 0, stream>>>(es2, invp + 32, norm2_w + H,
                                       Wexp + (size_t)NE * H * H, experts,
                                       out2);
  k_fstate<<<B, 256, 0, stream>>>(es2, out2, final_norm_w, fst);
  k_logits<<<940, 256, 0, stream>>>(fst, lm_head, part);
  k_comb<<<(B * V + 255) / 256, 256, 0, stream>>>(part, outp);
}

// Round 5
// 334.827 us; speedup vs baseline: 1.0585x; 1.0585x over previous
//
#include <hip/hip_runtime.h>
#include <cstddef>

#define H 1024
#define V 15000
#define NE 4
#define B 32
#define S 2048
#define EPS 1e-6f
#define CH 16
#define T0 128  // S / CH
#define NU 938  // ceil(V/16)

__device__ __forceinline__ float wave_sum(float x) {
#pragma unroll
  for (int off = 32; off > 0; off >>= 1) x += __shfl_down(x, off);
  return x;
}

// K1: per-vocab-row inverse RMS of embedding. one wave per row.
__global__ __launch_bounds__(256) void k_vocab(const float* __restrict__ emb,
                                               float* __restrict__ invr1) {
  const int gw = (blockIdx.x * blockDim.x + threadIdx.x) >> 6;  // row
  const int lane = threadIdx.x & 63;
  if (gw >= V) return;
  const float4* row = (const float4*)(emb + (size_t)gw * H);
  float s = 0.f;
#pragma unroll
  for (int j = 0; j < 4; ++j) {
    const float4 f = row[lane + 64 * j];
    s += f.x * f.x + f.y * f.y + f.z * f.z + f.w * f.w;
  }
  s = wave_sum(s);
  if (lane == 0) invr1[gw] = rsqrtf(s * (1.f / H) + EPS);
}

// Bucket b's by expert id (serial, trivial).
__global__ void k_bucket(const int* __restrict__ experts,
                         int* __restrict__ elist, int* __restrict__ ecnt) {
  if (threadIdx.x == 0 && blockIdx.x == 0) {
    int c[NE] = {0, 0, 0, 0};
    for (int b = 0; b < B; ++b) {
      const int e = experts[b];
      elist[e * B + c[e]] = b;
      c[e]++;
    }
    for (int e = 0; e < NE; ++e) ecnt[e] = c[e];
  }
}

// Phase A: per-chunk local layer-1 scans (zero initial state).
__global__ __launch_bounds__(1024, 8) void k_scanA(
    const int* __restrict__ windows, const float* __restrict__ emb,
    const float* __restrict__ norm1_w, const float* __restrict__ decay_logit,
    const float* __restrict__ invr1, float* __restrict__ local1) {
  __shared__ int tok_l[T0];
  __shared__ float iv_l[T0];
  const int b = blockIdx.x / CH, c = blockIdx.x % CH;
  const int h = threadIdx.x;
  if (h < T0) {
    const int tok = windows[b * S + c * T0 + h];
    tok_l[h] = tok << 10;
    iv_l[h] = invr1[tok];
  }
  const float d1 = 1.f / (1.f + expf(-decay_logit[h]));
  const float gw = norm1_w[h] * (1.f - d1);
  __syncthreads();
  float s = 0.f;
  for (int t0 = 0; t0 < T0; t0 += 8) {
    float e[8], cv[8];
#pragma unroll
    for (int k = 0; k < 8; ++k) {
      e[k] = emb[(size_t)tok_l[t0 + k] + h];
      cv[k] = iv_l[t0 + k] * gw;
    }
#pragma unroll
    for (int k = 0; k < 8; ++k) s = s * d1 + e[k] * cv[k];
  }
  local1[(size_t)(b * CH + c) * H + h] = s;
}

// Phase B: combine chunk locals -> chunk-start states, es1, pooled invRMS.
__global__ __launch_bounds__(1024) void k_scanB(
    const int* __restrict__ windows, const float* __restrict__ emb,
    const float* __restrict__ decay_logit, const float* __restrict__ local1,
    float* __restrict__ s1start, float* __restrict__ es1,
    float* __restrict__ invp) {
  __shared__ float red[16];
  const int b = blockIdx.x, h = threadIdx.x;
  const float d1 = 1.f / (1.f + expf(-decay_logit[h]));
  float dT = d1;
#pragma unroll
  for (int i = 0; i < 7; ++i) dT *= dT;  // d1^128
  float Sv = 0.f;
  for (int c = 0; c < CH; ++c) {
    const size_t idx = (size_t)(b * CH + c) * H + h;
    s1start[idx] = Sv;
    Sv = dT * Sv + local1[idx];
  }
  const int tl = windows[b * S + S - 1];
  const float v = emb[(size_t)tl * H + h] + Sv;
  es1[b * H + h] = v;
  const float q = wave_sum(v * v);
  if ((h & 63) == 0) red[h >> 6] = q;
  __syncthreads();
  if (h == 0) {
    float t = 0.f;
#pragma unroll
    for (int i = 0; i < 16; ++i) t += red[i];
    invp[b] = rsqrtf(t * (1.f / H) + EPS);
  }
}

// K4 v2: expert-grouped matvec. Block = (e, 16-row group); each W row is
// loaded once and dotted against all b's routed to expert e.
// out[b,dd] = relu(invp[b] * sum_h W[e,dd,h]*src[b,h]*n2w[h])
__global__ __launch_bounds__(256) void k_expert2(
    const float* __restrict__ src, const float* __restrict__ invp,
    const float* __restrict__ n2w, const float* __restrict__ Wl,
    const int* __restrict__ elist, const int* __restrict__ ecnt,
    float* __restrict__ outp) {
  const int e = blockIdx.x >> 6;     // 0..3
  const int dgrp = blockIdx.x & 63;  // 16 rows each
  const int cnt = ecnt[e];
  if (cnt == 0) return;
  const int wave = threadIdx.x >> 6, lane = threadIdx.x & 63;
  const float* W = Wl + (size_t)e * H * H;
  const float4* n2w4 = (const float4*)n2w;
#pragma unroll 1
  for (int i = 0; i < 4; ++i) {
    const int dd = dgrp * 16 + wave * 4 + i;
    const float4* wr4 = (const float4*)(W + (size_t)dd * H);
    float4 w4[4];
#pragma unroll
    for (int j = 0; j < 4; ++j) w4[j] = wr4[lane + 64 * j];
#pragma unroll 1
    for (int bi = 0; bi < cnt; ++bi) {
      const int b = elist[e * B + bi];
      const float4* s4 = (const float4*)(src + b * H);
      float s = 0.f;
#pragma unroll
      for (int j = 0; j < 4; ++j) {
        const float4 sv = s4[lane + 64 * j];
        const float4 nv = n2w4[lane + 64 * j];
        s += w4[j].x * sv.x * nv.x + w4[j].y * sv.y * nv.y +
             w4[j].z * sv.z * nv.z + w4[j].w * sv.w * nv.w;
      }
      s = wave_sum(s);
      if (lane == 0) outp[b * H + dd] = fmaxf(s * invp[b], 0.f);
    }
  }
}

// Fused phase C+D: one emb gather sweep. Per (b,chunk) block over all H:
// recompute s1 from chunk starts, write x1 to LDS, per-timestep wave-reduce
// sum(x1^2) -> rinv in LDS, then continue the layer-2 scan reading x1 back.
__global__ __launch_bounds__(1024, 8) void k_fuseCD(
    const int* __restrict__ windows, const float* __restrict__ emb,
    const float* __restrict__ norm1_w, const float* __restrict__ decay_logit,
    const float* __restrict__ invr1, const float* __restrict__ s1start,
    const float* __restrict__ out1, float* __restrict__ local2,
    float* __restrict__ x1last) {
  __shared__ int tok_l[T0];
  __shared__ float iv_l[T0];
  __shared__ float q[16 * H];  // 64 KB: x1 values for 16 timesteps
  __shared__ float rinv_l[16];
  const int b = blockIdx.x / CH, c = blockIdx.x % CH;
  const int h = threadIdx.x;
  if (h < T0) {
    const int tok = windows[b * S + c * T0 + h];
    tok_l[h] = tok << 10;
    iv_l[h] = invr1[tok];
  }
  const float d1 = 1.f / (1.f + expf(-decay_logit[h]));
  const float g1 = norm1_w[h] * (1.f - d1);
  const float d2 = 1.f / (1.f + expf(-decay_logit[H + h]));
  const float g2 = norm1_w[H + h] * (1.f - d2);
  const float o1 = out1[b * H + h];
  float s1 = s1start[(size_t)(b * CH + c) * H + h];
  __syncthreads();
  const int wv = h >> 6, lane = h & 63;
  float s2 = 0.f;
  for (int sb = 0; sb < T0 / 16; ++sb) {
#pragma unroll
    for (int g = 0; g < 2; ++g) {
      float e[8], cv[8];
#pragma unroll
      for (int k = 0; k < 8; ++k) {
        const int t = sb * 16 + g * 8 + k;
        e[k] = emb[(size_t)tok_l[t] + h];
        cv[k] = iv_l[t] * g1;
      }
#pragma unroll
      for (int k = 0; k < 8; ++k) {
        s1 = s1 * d1 + e[k] * cv[k];
        q[(g * 8 + k) * H + h] = e[k] + s1 + o1;
      }
    }
    __syncthreads();
    // wave wv reduces timestep wv: sum of squares -> rinv
    const float4* q4 = (const float4*)(q + wv * H);
    float ssum = 0.f;
#pragma unroll
    for (int j = 0; j < 4; ++j) {
      const float4 f = q4[lane + 64 * j];
      ssum += f.x * f.x + f.y * f.y + f.z * f.z + f.w * f.w;
    }
    ssum = wave_sum(ssum);
    if (lane == 0) rinv_l[wv] = rsqrtf(ssum * (1.f / H) + EPS);
    __syncthreads();
    // layer-2 scan over these 16 timesteps (x1 read back from LDS)
#pragma unroll
    for (int g = 0; g < 2; ++g) {
      float xv[8], rc[8];
#pragma unroll
      for (int k = 0; k < 8; ++k) {
        xv[k] = q[(g * 8 + k) * H + h];
        rc[k] = rinv_l[g * 8 + k] * g2;
      }
#pragma unroll
      for (int k = 0; k < 8; ++k) s2 = s2 * d2 + xv[k] * rc[k];
    }
    __syncthreads();  // protect q before next sub-block overwrites
  }
  local2[(size_t)(b * CH + c) * H + h] = s2;
  if (c == CH - 1) x1last[b * H + h] = q[15 * H + h];
}

// Phase E: combine layer-2 chunk locals -> es2 + pooled invRMS.
__global__ __launch_bounds__(1024) void k_scanE(
    const float* __restrict__ decay_logit, const float* __restrict__ local2,
    const float* __restrict__ x1last, float* __restrict__ es2,
    float* __restrict__ invp) {
  __shared__ float red[16];
  const int b = blockIdx.x, h = threadIdx.x;
  const float d2 = 1.f / (1.f + expf(-decay_logit[H + h]));
  float dT = d2;
#pragma unroll
  for (int i = 0; i < 7; ++i) dT *= dT;  // d2^128
  float Sv = 0.f;
  for (int c = 0; c < CH; ++c)
    Sv = dT * Sv + local2[(size_t)(b * CH + c) * H + h];
  const float v = x1last[b * H + h] + Sv;
  es2[b * H + h] = v;
  const float q = wave_sum(v * v);
  if ((h & 63) == 0) red[h >> 6] = q;
  __syncthreads();
  if (h == 0) {
    float t = 0.f;
#pragma unroll
    for (int i = 0; i < 16; ++i) t += red[i];
    invp[32 + b] = rsqrtf(t * (1.f / H) + EPS);
  }
}

// K7: final residual + final RMSNorm -> fstate
__global__ __launch_bounds__(256) void k_fstate(const float* __restrict__ es2,
    const float* __restrict__ out2, const float* __restrict__ fnw,
    float* __restrict__ fst) {
  __shared__ float red[4];
  const int b = blockIdx.x, tid = threadIdx.x;
  float4 x = ((const float4*)(es2 + b * H))[tid];
  const float4 y = ((const float4*)(out2 + b * H))[tid];
  x.x += y.x; x.y += y.y; x.z += y.z; x.w += y.w;
  float s = x.x * x.x + x.y * x.y + x.z * x.z + x.w * x.w;
  s = wave_sum(s);
  if ((tid & 63) == 0) red[tid >> 6] = s;
  __syncthreads();
  const float ir =
      rsqrtf((red[0] + red[1] + red[2] + red[3]) * (1.f / H) + EPS);
  const float4 w = ((const float4*)fnw)[tid];
  float4 o;
  o.x = x.x * ir * w.x; o.y = x.y * ir * w.y;
  o.z = x.z * ir * w.z; o.w = x.w * ir * w.w;
  ((float4*)(fst + b * H))[tid] = o;
}

// K8: split-K register-blocked skinny GEMM (unchanged from R4).
__global__ __launch_bounds__(256) void k_logits(const float* __restrict__ fst,
    const float* __restrict__ lm, float* __restrict__ part) {
  __shared__ float4 fs4[16 * 128];  // 32 KB
  const int hh = blockIdx.x & 1;
  const int bgrp = (blockIdx.x >> 1) & 1;
  const int vblk = blockIdx.x >> 2;  // 0..234
  const int tid = threadIdx.x;
  for (int j = tid; j < 16 * 128; j += 256) {
    const int bb = j >> 7, q = j & 127;
    fs4[j] = ((const float4*)fst)[(bgrp * 16 + bb) * 256 + hh * 128 + q];
  }
  __syncthreads();
  const int wave = tid >> 6, lane = tid & 63;
  const int sg = lane >> 4;   // 0..3
  const int c = lane & 15;    // 0..15
  const int u = vblk * 4 + wave;
  if (u >= NU) return;
  const int v0 = u * 16 + sg * 4;
  const float4* rp[4];
#pragma unroll
  for (int i = 0; i < 4; ++i) {
    int r = v0 + i;
    if (r > V - 1) r = V - 1;
    rp[i] = (const float4*)(lm + (size_t)r * H) + hh * 128;
  }
  float acc[4][16];
#pragma unroll
  for (int i = 0; i < 4; ++i)
#pragma unroll
    for (int bb = 0; bb < 16; ++bb) acc[i][bb] = 0.f;
  float4 lv[4], lvn[4];
#pragma unroll
  for (int i = 0; i < 4; ++i) lv[i] = rp[i][c];
#pragma unroll 1
  for (int jj = 0; jj < 8; ++jj) {
    const int hoff = c + 16 * jj;
    if (jj < 7) {
#pragma unroll
      for (int i = 0; i < 4; ++i) lvn[i] = rp[i][hoff + 16];
    }
#pragma unroll
    for (int bb = 0; bb < 16; ++bb) {
      const float4 fv = fs4[bb * 128 + hoff];
#pragma unroll
      for (int i = 0; i < 4; ++i) {
        acc[i][bb] += lv[i].x * fv.x + lv[i].y * fv.y + lv[i].z * fv.z +
                      lv[i].w * fv.w;
      }
    }
#pragma unroll
    for (int i = 0; i < 4; ++i) lv[i] = lvn[i];
  }
#pragma unroll
  for (int off = 1; off < 16; off <<= 1)
#pragma unroll
    for (int i = 0; i < 4; ++i)
#pragma unroll
      for (int bb = 0; bb < 16; ++bb)
        acc[i][bb] += __shfl_xor(acc[i][bb], off);
  if (c == 0) {
    float* pdst = part + (size_t)hh * B * V + (size_t)bgrp * 16 * V;
#pragma unroll
    for (int bb = 0; bb < 16; ++bb)
#pragma unroll
      for (int i = 0; i < 4; ++i) {
        const int r = v0 + i;
        if (r < V) pdst[(size_t)bb * V + r] = acc[i][bb];
      }
  }
}

// K9: combine split-K partials.
__global__ __launch_bounds__(256) void k_comb(const float* __restrict__ part,
                                              float* __restrict__ outp) {
  const int i = blockIdx.x * 256 + threadIdx.x;
  if (i < B * V) outp[i] = part[i] + part[B * V + i];
}

extern "C" void kernel_launch(void* const* d_in, const int* in_sizes, int n_in,
                              void* d_out, int out_size, void* d_ws,
                              size_t ws_size, hipStream_t stream) {
  const int* windows = (const int*)d_in[0];
  const int* experts = (const int*)d_in[2];
  const float* emb = (const float*)d_in[3];
  const float* norm1_w = (const float*)d_in[4];
  const float* decay_logit = (const float*)d_in[5];
  const float* norm2_w = (const float*)d_in[6];
  const float* Wexp = (const float*)d_in[7];
  const float* final_norm_w = (const float*)d_in[8];
  const float* lm_head = (const float*)d_in[9];
  float* outp = (float*)d_out;

  float* ws = (float*)d_ws;
  float* invr1 = ws;                       // 15360
  float* local1 = invr1 + 15360;           // B*CH*H
  float* s1start = local1 + B * CH * H;    // B*CH*H
  float* local2 = s1start + B * CH * H;    // B*CH*H
  float* out1 = local2 + B * CH * H;       // B*H
  float* out2 = out1 + B * H;              // B*H
  float* es1 = out2 + B * H;               // B*H
  float* es2 = es1 + B * H;                // B*H
  float* x1last = es2 + B * H;             // B*H
  float* fst = x1last + B * H;             // B*H
  float* invp = fst + B * H;               // 64
  int* elist = (int*)(invp + 64);          // NE*B ints
  int* ecnt = elist + NE * B;              // NE ints
  // part aliases local1+s1start (1.05M floats, dead by k_logits time);
  // needs 2*B*V = 960000 floats. local2 (consumed by scanE) untouched.
  float* part = local1;

  k_vocab<<<(V * 64 + 255) / 256, 256, 0, stream>>>(emb, invr1);
  k_bucket<<<1, 64, 0, stream>>>(experts, elist, ecnt);
  k_scanA<<<B * CH, 1024, 0, stream>>>(windows, emb, norm1_w, decay_logit,
                                       invr1, local1);
  k_scanB<<<B, 1024, 0, stream>>>(windows, emb, decay_logit, local1, s1start,
                                  es1, invp);
  k_expert2<<<NE * 64, 256, 0, stream>>>(es1, invp, norm2_w, Wexp, elist,
                                         ecnt, out1);
  k_fuseCD<<<B * CH, 1024, 0, stream>>>(windows, emb, norm1_w, decay_logit,
                                        invr1, s1start, out1, local2, x1last);
  k_scanE<<<B, 1024, 0, stream>>>(decay_logit, local2, x1last, es2, invp);
  k_expert2<<<NE * 64, 256, 0, stream>>>(es2, invp + 32, norm2_w + H,
                                         Wexp + (size_t)NE * H * H, elist,
                                         ecnt, out2);
  k_fstate<<<B, 256, 0, stream>>>(es2, out2, final_norm_w, fst);
  k_logits<<<940, 256, 0, stream>>>(fst, lm_head, part);
  k_comb<<<(B * V + 255) / 256, 256, 0, stream>>>(part, outp);
}